// Round 9
// baseline (199.143 us; speedup 1.0000x reference)
//
#include <hip/hip_runtime.h>
#include <cmath>

// Problem constants
#define B_  4
#define S_  4096
#define D_  256
#define H_  4
#define DH_ 64
#define M_TOTAL (B_*S_)   // 16384
#define QSCALE 0.1803368801111f   // 0.125 * log2(e), folded into Wq

typedef __bf16 bf16x8 __attribute__((ext_vector_type(8)));
typedef __bf16 bf16x4 __attribute__((ext_vector_type(4)));
typedef __bf16 bf16x2 __attribute__((ext_vector_type(2)));
typedef float  f32x4  __attribute__((ext_vector_type(4)));
typedef float  f32x16 __attribute__((ext_vector_type(16)));

#define AS1 __attribute__((address_space(1)))
#define AS3 __attribute__((address_space(3)))

__device__ __forceinline__ void g2lds16(const void* g, void* l) {
    __builtin_amdgcn_global_load_lds((AS1 const void*)g, (AS3 void*)l, 16, 0, 0);
}

// Half-wave dword exchange: a' = {a.lo, b.lo}, b' = {a.hi, b.hi}
#if __has_builtin(__builtin_amdgcn_permlane32_swap)
typedef unsigned uint2v __attribute__((ext_vector_type(2)));
__device__ __forceinline__ void plswap(unsigned &a, unsigned &b) {
    uint2v r = __builtin_amdgcn_permlane32_swap(a, b, false, false);
    a = r[0]; b = r[1];
}
#else
__device__ __forceinline__ void plswap(unsigned &a, unsigned &b) {
    unsigned bl = (unsigned)__shfl_xor((int)b, 32);
    unsigned ah = (unsigned)__shfl_xor((int)a, 32);
    bool hi = (threadIdx.x & 32) != 0;
    unsigned na = hi ? bl : a;
    unsigned nb = hi ? b  : ah;
    a = na; b = nb;
}
#endif

__device__ __forceinline__ unsigned pk2(float x, float y) {
    bf16x2 t; t[0] = (__bf16)x; t[1] = (__bf16)y;
    return __builtin_bit_cast(unsigned, t);
}

// ---------------------------------------------------------------------------
// Kernel: prep = cast X fp32->bf16 (blocks 0..2047, 8 elems/thread)
//              + transpose 4 weights fp32 -> bf16 Wt[n][k] (blocks 2048..2303)
// Wq additionally scaled by QSCALE (folds attention scale + log2e into Q).
// ---------------------------------------------------------------------------
__global__ __launch_bounds__(256) void prep(const float* __restrict__ X,
                                            const float* __restrict__ W0,
                                            const float* __restrict__ W1,
                                            const float* __restrict__ W2,
                                            const float* __restrict__ W3,
                                            __bf16* __restrict__ Xb,
                                            __bf16* __restrict__ Wt_all) {
    int t = threadIdx.x;
    if (blockIdx.x < 2048) {
        size_t i = ((size_t)blockIdx.x * 256 + t) * 8;
        float4 v0 = *(const float4*)(X + i);
        float4 v1 = *(const float4*)(X + i + 4);
        bf16x8 o;
        o[0] = (__bf16)v0.x; o[1] = (__bf16)v0.y; o[2] = (__bf16)v0.z; o[3] = (__bf16)v0.w;
        o[4] = (__bf16)v1.x; o[5] = (__bf16)v1.y; o[6] = (__bf16)v1.z; o[7] = (__bf16)v1.w;
        *(bf16x8*)(Xb + i) = o;
        return;
    }
    int bid = blockIdx.x - 2048;
    int z = bid >> 6, rem = bid & 63;
    int by = rem >> 3, bx = rem & 7;
    const float* W = (z == 0) ? W0 : (z == 1) ? W1 : (z == 2) ? W2 : W3;
    float wsc = (z == 0) ? QSCALE : 1.0f;
    __bf16* Wt = Wt_all + (size_t)z * 65536;
    __shared__ float tile[32][33];
    int r0 = by * 32, c0 = bx * 32;
#pragma unroll
    for (int e = 0; e < 4; e++) {
        int idx = t + e * 256; int r = idx >> 5, c = idx & 31;
        tile[r][c] = W[(r0 + r) * 256 + c0 + c];
    }
    __syncthreads();
#pragma unroll
    for (int e = 0; e < 4; e++) {
        int idx = t + e * 256; int r = idx >> 5, c = idx & 31;
        Wt[(c0 + r) * 256 + (r0 + c)] = (__bf16)(tile[c][r] * wsc);
    }
}

// ---------------------------------------------------------------------------
// Kernel: NT GEMM  C[m][n] = sum_k A[m][k] * Wt[n][k] + bias[n]
// z=0 -> bf16 row-major Q into outb; z=1 -> K in MFMA-FRAGMENT order (Kfrag);
// z=2 -> V in MFMA-FRAGMENT order (Vfrag). out_is_f32 -> fp32 into outf.
//
// Fragment layouts (consumed by attn as 1KB coalesced global loads):
//  Kfrag idx = (((bh*64+tile)*2+kw)*4+ks)*512 + (hh*32+l31)*8 + e
//    holds K[b][s = tile*64+kw*32+l31][hd*64 + ks*16 + hh*8 + e], bh = b*4+hd
//  Vfrag idx = (((bh*64+tile)*4+tks)*2+mt)*512 + (hh*32+l31)*8 + e
//    holds V[b][s = tile*64+tks*16+hh*8+e][hd*64 + mt*32 + l31]
// ---------------------------------------------------------------------------
__global__ __launch_bounds__(256) void gemm_bt(const __bf16* __restrict__ A,
                                               const __bf16* __restrict__ Wt_all,
                                               const float* __restrict__ bias0,
                                               const float* __restrict__ bias1,
                                               const float* __restrict__ bias2,
                                               __bf16* __restrict__ outb,
                                               __bf16* __restrict__ koutb,
                                               __bf16* __restrict__ voutb,
                                               float* __restrict__ outf,
                                               int out_is_f32, float bsc0) {
    constexpr int K = 256;
    __shared__ __attribute__((aligned(16))) __bf16 As[128 * 32];
    __shared__ __attribute__((aligned(16))) __bf16 Bs[128 * 32];

    int t = threadIdx.x;
    int lane = t & 63, w = t >> 6;
    int wr = w >> 1, wc = w & 1;
    int l16 = lane & 15, quad = lane >> 4;
    int mbase = blockIdx.x * 128;
    int nbase = blockIdx.y * 128;
    int z = blockIdx.z;
    const __bf16* Bt = Wt_all + (size_t)z * 65536;
    const float* bias = (z == 0) ? bias0 : (z == 1) ? bias1 : bias2;
    float bscale = (z == 0) ? bsc0 : 1.0f;

    f32x4 acc[4][4] = {};

    int srow = t >> 2;
    int sseg = (t & 3) * 8;

    for (int kk = 0; kk < K; kk += 32) {
        __syncthreads();
        g2lds16(A  + (size_t)(mbase +      srow) * K + kk + sseg, (char*)As +        t * 16);
        g2lds16(A  + (size_t)(mbase + 64 + srow) * K + kk + sseg, (char*)As + 4096 + t * 16);
        g2lds16(Bt + (size_t)(nbase +      srow) * K + kk + sseg, (char*)Bs +        t * 16);
        g2lds16(Bt + (size_t)(nbase + 64 + srow) * K + kk + sseg, (char*)Bs + 4096 + t * 16);
        __syncthreads();

        bf16x8 a[4], b[4];
#pragma unroll
        for (int i = 0; i < 4; i++)
            a[i] = *(const bf16x8*)(As + (wr * 64 + i * 16 + l16) * 32 + quad * 8);
#pragma unroll
        for (int j = 0; j < 4; j++)
            b[j] = *(const bf16x8*)(Bs + (wc * 64 + j * 16 + l16) * 32 + quad * 8);
#pragma unroll
        for (int i = 0; i < 4; i++)
#pragma unroll
            for (int j = 0; j < 4; j++)
                acc[i][j] = __builtin_amdgcn_mfma_f32_16x16x32_bf16(a[i], b[j], acc[i][j], 0, 0, 0);
    }

#pragma unroll
    for (int i = 0; i < 4; i++) {
#pragma unroll
        for (int j = 0; j < 4; j++) {
            int col = nbase + wc * 64 + j * 16 + l16;
            float bv = bias[col] * bscale;
            int row0 = mbase + wr * 64 + i * 16 + quad * 4;
            if (out_is_f32) {
#pragma unroll
                for (int r = 0; r < 4; r++)
                    outf[(size_t)(row0 + r) * 256 + col] = acc[i][j][r] + bv;
            } else if (z == 2) {
                // V -> Vfrag (4 consecutive keys = 4 consecutive e within one
                // 8-elem group since row0 % 4 == 0)
                int hd = col >> 6, dh = col & 63;
                int mt = dh >> 5, l31v = dh & 31;
                int bidx = row0 >> 12, s0 = row0 & 4095;
                int tile = s0 >> 6, tks = (s0 >> 4) & 3, hhk = (s0 >> 3) & 1;
                int bh2 = bidx * 4 + hd;
                size_t addr = ((((size_t)bh2 * 64 + tile) * 4 + tks) * 2 + mt) * 512
                              + (hhk * 32 + l31v) * 8 + (s0 & 7);
                bf16x4 pk;
#pragma unroll
                for (int r = 0; r < 4; r++) pk[r] = (__bf16)(acc[i][j][r] + bv);
                *(bf16x4*)(voutb + addr) = pk;
            } else if (z == 1) {
                // K -> Kfrag (scalar stores; r advances l31 -> stride 8 elems)
                int hd = col >> 6, n6 = col & 63;
                int ks = (n6 >> 4) & 3, hhq = (n6 >> 3) & 1, e = n6 & 7;
                int bidx = row0 >> 12, s0 = row0 & 4095;
                int tile = s0 >> 6, kwv = (s0 >> 5) & 1, l31k = s0 & 31;
                int bh2 = bidx * 4 + hd;
                size_t addr = ((((size_t)bh2 * 64 + tile) * 2 + kwv) * 4 + ks) * 512
                              + (hhq * 32 + l31k) * 8 + e;
#pragma unroll
                for (int r = 0; r < 4; r++)
                    koutb[addr + (size_t)r * 8] = (__bf16)(acc[i][j][r] + bv);
            } else {
#pragma unroll
                for (int r = 0; r < 4; r++)
                    outb[(size_t)(row0 + r) * 256 + col] = (__bf16)(acc[i][j][r] + bv);
            }
        }
    }
}

// ---------------------------------------------------------------------------
// Kernel: flash attention, S^T form, 32x32x16 MFMA, in-register P.
// 512 blocks x 4 waves (256 thr), 2x2 split: kw = w&1 (key half),
// qw2 = w>>1 (query half); 32 keys x 64 queries per wave per 64-key tile.
//
// R9 (fix of R8's latency stall): K/V in MFMA-fragment order (verified R8),
// NO LDS in main loop, but now EVERY load has >=1 full body of latency
// coverage:
//   body(it): KLOAD(it+2)->kfN | VLOAD(it+1)->vfN | SMPV(tile it, vfC loaded
//             last body) | QKMFMA(kfC loaded 2 bodies ago) -> scores(it+1).
// To afford the V double-buffer (+16 regs) at the hard 256-reg/wave cap
// (2 waves/SIMD), st is SINGLE-buffered: QKMFMA moved AFTER SMPV (WAR on
// st, 32 AGPRs saved vs R5/R8's st double-buffer). Cost: next body's exp2
// waits on a ~100cy MFMA chain issued at prev body end (partly hidden by
// the co-resident wave); gain: removes R8's per-body V-load stall (~28%
// idle). Budget: kf 32 + vf 32 + qf 32 + st 32 + acc 64 + temps ~45 = ~237.
// R8's FETCH=13MB proved L2/L3 absorb all KV re-reads (KV 1MB/head, 2
// heads/XCD L2). Spill signature = FETCH >> 50MB.
// Q pre-scaled by 0.125*log2e -> p = exp2(s). XCD swizzle: 2 heads per XCD.
// ---------------------------------------------------------------------------
__global__ __launch_bounds__(256, 2) void attn(const __bf16* __restrict__ Qb,
                                               const __bf16* __restrict__ Kf,
                                               const __bf16* __restrict__ Vf,
                                               __bf16* __restrict__ Ctx) {
    // LDS: epilogue only. [0,32K) acc dumps (2x16KB), [32K,33K) lsum dumps,
    // [36864,55296) 2 x (64 x 72) bf16 transpose tiles.
    __shared__ __attribute__((aligned(16))) __bf16 smem[32768];

    int t = threadIdx.x;
    int lane = t & 63, w = t >> 6;
    int l31 = lane & 31, hh = lane >> 5;
    int kw = w & 1, qw2 = w >> 1;

    // XCD swizzle: lin%8 = XCD; 2 heads per XCD
    int lin = blockIdx.x;
    int xcd = lin & 7, j = lin >> 3;
    int bh = xcd * 2 + (j & 1);
    int qblk = j >> 1;               // 0..31
    int b = bh >> 2, hd = bh & 3;
    int qw = qblk * 128 + qw2 * 64;  // this wave's first query

    const __bf16* Kbh = Kf + (size_t)bh * 262144;   // 64 tiles * 8 frags * 512
    const __bf16* Vbh = Vf + (size_t)bh * 262144;

    // Q B-fragments (pre-scaled): n = query = qt*32+l31, k = dh = ks*16+hh*8+e
    bf16x8 qf[4][2];
#pragma unroll
    for (int ks = 0; ks < 4; ks++)
#pragma unroll
        for (int qt = 0; qt < 2; qt++)
            qf[ks][qt] = *(const bf16x8*)(Qb + (size_t)(b * S_ + qw + qt * 32 + l31) * 256
                                              + hd * 64 + ks * 16 + hh * 8);

    f32x16 acc[2][2] = {};   // [mt][qt]: dh = mt*32+..., query = qt*32+l31
    float lsum[2] = {0.f, 0.f};

    int kw4 = kw * 4;
    int kw2 = kw * 2;

    // Coalesced fragment loads (1KB per instruction)
#define KLOAD(TILE, KF) do {                                                   \
        const __bf16* Kp = Kbh + ((TILE) * 8 + kw4) * 512 + lane * 8;          \
        _Pragma("unroll")                                                      \
        for (int ks = 0; ks < 4; ks++)                                         \
            KF[ks] = *(const bf16x8*)(Kp + ks * 512);                          \
    } while (0)

#define VLOAD(TILE, VV) do {                                                   \
        const __bf16* Vp = Vbh + (TILE) * 4096 + kw2 * 1024 + lane * 8;        \
        _Pragma("unroll")                                                      \
        for (int tm = 0; tm < 4; tm++)                                         \
            VV[tm] = *(const bf16x8*)(Vp + tm * 512);                          \
    } while (0)

    // QK^T MFMAs from pre-loaded K fragments (into single st)
#define QKMFMA(KF) do {                                                        \
        _Pragma("unroll")                                                      \
        for (int qt = 0; qt < 2; qt++) st[qt] = (f32x16){};                    \
        _Pragma("unroll")                                                      \
        for (int ks = 0; ks < 4; ks++)                                         \
            _Pragma("unroll")                                                  \
            for (int qt = 0; qt < 2; qt++)                                     \
                st[qt] = __builtin_amdgcn_mfma_f32_32x32x16_bf16(              \
                    KF[ks], qf[ks][qt], st[qt], 0, 0, 0);                      \
    } while (0)

    // softmax + PV for scores in st using pre-loaded V fragments VV
#define SMPV(VV) do {                                                          \
        unsigned dd[2][8];                                                     \
        _Pragma("unroll")                                                      \
        for (int qt = 0; qt < 2; qt++) {                                       \
            float p[16];                                                       \
            _Pragma("unroll")                                                  \
            for (int r = 0; r < 16; r++)                                       \
                p[r] = __builtin_amdgcn_exp2f(st[qt][r]);                      \
            float s0 = ((p[0]+p[1])+(p[2]+p[3]))+((p[4]+p[5])+(p[6]+p[7]));    \
            float s1 = ((p[8]+p[9])+(p[10]+p[11]))+((p[12]+p[13])+(p[14]+p[15])); \
            lsum[qt] += s0 + s1;                                               \
            _Pragma("unroll")                                                  \
            for (int m = 0; m < 4; m++) {                                      \
                dd[qt][m*2]   = pk2(p[4*m],   p[4*m+1]);                       \
                dd[qt][m*2+1] = pk2(p[4*m+2], p[4*m+3]);                       \
            }                                                                  \
        }                                                                      \
        _Pragma("unroll")                                                      \
        for (int tt = 0; tt < 2; tt++) {                                       \
            bf16x8 pf[2];                                                      \
            _Pragma("unroll")                                                  \
            for (int qt = 0; qt < 2; qt++) {                                   \
                unsigned x0 = dd[qt][4*tt],   y0 = dd[qt][4*tt+2];             \
                unsigned x1 = dd[qt][4*tt+1], y1 = dd[qt][4*tt+3];             \
                plswap(x0, y0);                                                \
                plswap(x1, y1);                                                \
                union { unsigned u[4]; bf16x8 v; } c;                          \
                c.u[0] = x0; c.u[1] = x1; c.u[2] = y0; c.u[3] = y1;            \
                pf[qt] = c.v;                                                  \
            }                                                                  \
            _Pragma("unroll")                                                  \
            for (int mt = 0; mt < 2; mt++) {                                   \
                bf16x8 vf = VV[tt * 2 + mt];                                   \
                _Pragma("unroll")                                              \
                for (int qt = 0; qt < 2; qt++)                                 \
                    acc[mt][qt] = __builtin_amdgcn_mfma_f32_32x32x16_bf16(     \
                        vf, pf[qt], acc[mt][qt], 0, 0, 0);                     \
            }                                                                  \
        }                                                                      \
    } while (0)

    // Pipeline body. Entering body(it): st = scores(it) [QK'd end of body
    // it-1], KC = K(it+1) [loaded body it-1], VC = V(it) [loaded body it-1].
#define BODY(IT, KN, KC, VN, VC) do {                                          \
        if ((IT) < 62) KLOAD((IT) + 2, KN);                                    \
        if ((IT) < 63) VLOAD((IT) + 1, VN);                                    \
        SMPV(VC);                                                              \
        if ((IT) < 63) QKMFMA(KC);                                             \
    } while (0)

    bf16x8 kfA[4], kfB[4], vfA[4], vfB[4];
    f32x16 st[2];

    // Prologue: overlap the three initial load groups, then QK(0) -> st.
    KLOAD(0, kfA);
    KLOAD(1, kfB);
    VLOAD(0, vfA);
    QKMFMA(kfA);   // scores(0); kfA free afterwards

    for (int it = 0; it < 64; it += 2) {
        BODY(it,     kfA, kfB, vfB, vfA);   // K(it+2)->kfA, V(it+1)->vfB
        BODY(it + 1, kfB, kfA, vfA, vfB);   // K(it+3)->kfB, V(it+2)->vfA
    }
#undef BODY
#undef SMPV
#undef QKMFMA
#undef VLOAD
#undef KLOAD

    // In-wave denom over this wave's keys (halves hold disjoint key sets)
#pragma unroll
    for (int qt = 0; qt < 2; qt++)
        lsum[qt] += __shfl_xor(lsum[qt], 32);

    // --- Cross-wave merge between kw partners (same qw2) ---
    __syncthreads();
    float* lsd = (float*)((char*)smem + 32768);
    if (kw == 1) {
#pragma unroll
        for (int mt = 0; mt < 2; mt++)
#pragma unroll
            for (int qt = 0; qt < 2; qt++)
#pragma unroll
                for (int g = 0; g < 4; g++) {
                    f32x4 v;
#pragma unroll
                    for (int e = 0; e < 4; e++) v[e] = acc[mt][qt][4 * g + e];
                    *(f32x4*)((char*)smem + qw2 * 16384
                              + ((mt * 2 + qt) * 4 + g) * 1024 + lane * 16) = v;
                }
        lsd[qw2 * 128 + lane * 2 + 0] = lsum[0];
        lsd[qw2 * 128 + lane * 2 + 1] = lsum[1];
    }
    __syncthreads();
    if (kw == 0) {
        float inv[2];
#pragma unroll
        for (int qt = 0; qt < 2; qt++)
            inv[qt] = 1.f / (lsum[qt] + lsd[qw2 * 128 + lane * 2 + qt]);
#pragma unroll
        for (int mt = 0; mt < 2; mt++)
#pragma unroll
            for (int qt = 0; qt < 2; qt++)
#pragma unroll
                for (int g = 0; g < 4; g++) {
                    f32x4 v = *(const f32x4*)((char*)smem + qw2 * 16384
                                              + ((mt * 2 + qt) * 4 + g) * 1024 + lane * 16);
#pragma unroll
                    for (int e = 0; e < 4; e++) acc[mt][qt][4 * g + e] += v[e];
                }

        // Epilogue: normalize, per-wave LDS transpose (64x72), coalesced store
        __bf16* Es = smem + 18432 + qw2 * 4608;   // bytes 36864 + qw2*9216
#pragma unroll
        for (int qt = 0; qt < 2; qt++)
#pragma unroll
            for (int mt = 0; mt < 2; mt++)
#pragma unroll
                for (int rg = 0; rg < 4; rg++) {
                    bf16x4 ov;
#pragma unroll
                    for (int e = 0; e < 4; e++)
                        ov[e] = (__bf16)(acc[mt][qt][4 * rg + e] * inv[qt]);
                    int dhb = mt * 32 + rg * 8 + 4 * hh;
                    *(bf16x4*)(Es + (qt * 32 + l31) * 72 + dhb) = ov;
                }
#pragma unroll
        for (int pass = 0; pass < 8; pass++) {
            int q = pass * 8 + (lane >> 3);
            int col = (lane & 7) * 8;
            bf16x8 val = *(const bf16x8*)(Es + q * 72 + col);
            *(bf16x8*)(Ctx + (size_t)(b * S_ + qw + q) * 256 + hd * 64 + col) = val;
        }
    }
}

// ---------------------------------------------------------------------------
extern "C" void kernel_launch(void* const* d_in, const int* in_sizes, int n_in,
                              void* d_out, int out_size, void* d_ws, size_t ws_size,
                              hipStream_t stream) {
    const float* X  = (const float*)d_in[0];
    const float* Wq = (const float*)d_in[1];
    const float* bq = (const float*)d_in[2];
    const float* Wk = (const float*)d_in[3];
    const float* bk = (const float*)d_in[4];
    const float* Wv = (const float*)d_in[5];
    const float* bv = (const float*)d_in[6];
    const float* Wo = (const float*)d_in[7];
    const float* bo = (const float*)d_in[8];
    float* out = (float*)d_out;

    char* ws = (char*)d_ws;
    const size_t MB = 1024 * 1024;
    // [0,8MB) Xb (bf16 X), dead after QKV gemm -> reused as Ctx
    // [8,8.5MB) Wt; [8.5,16.5) Qb; [16.5,24.5) Kf; [24.5,32.5) Vf
    __bf16* Xb  = (__bf16*)(ws);
    __bf16* Ctx = (__bf16*)(ws);
    __bf16* Wt  = (__bf16*)(ws + 8 * MB);
    __bf16* Qb  = (__bf16*)(ws + 8 * MB + 512 * 1024);
    __bf16* Kf  = (__bf16*)((char*)Qb + 8 * MB);
    __bf16* Vf  = (__bf16*)((char*)Kf + 8 * MB);

    // 1. cast X -> bf16 + transpose/scale weights (fused)
    prep<<<dim3(2304), dim3(256), 0, stream>>>(X, Wq, Wk, Wv, Wo, Xb, Wt);
    // 2. QKV projections; K and V written in MFMA-fragment order
    gemm_bt<<<dim3(M_TOTAL / 128, 2, 3), dim3(256), 0, stream>>>(
        Xb, Wt, bq, bk, bv, Qb, Kf, Vf, nullptr, 0, QSCALE);
    // 3. flash attention -> Ctx (512 blocks x 4 waves, barrier-free, all loads
    //    >=1-body ahead, single-st pipeline)
    attn<<<dim3(512), dim3(256), 0, stream>>>(Qb, Kf, Vf, Ctx);
    // 4. output projection (fp32 out + bias)
    gemm_bt<<<dim3(M_TOTAL / 128, 2, 1), dim3(256), 0, stream>>>(
        Ctx, Wt + 3 * 65536, bo, bo, bo, nullptr, nullptr, nullptr, out, 1, 1.0f);
}

// Round 10
// 180.566 us; speedup vs baseline: 1.1029x; 1.1029x over previous
//
#include <hip/hip_runtime.h>
#include <cmath>

// Problem constants
#define B_  4
#define S_  4096
#define D_  256
#define H_  4
#define DH_ 64
#define M_TOTAL (B_*S_)   // 16384
#define QSCALE 0.1803368801111f   // 0.125 * log2(e), folded into Wq

typedef __bf16 bf16x8 __attribute__((ext_vector_type(8)));
typedef __bf16 bf16x4 __attribute__((ext_vector_type(4)));
typedef __bf16 bf16x2 __attribute__((ext_vector_type(2)));
typedef float  f32x4  __attribute__((ext_vector_type(4)));
typedef float  f32x16 __attribute__((ext_vector_type(16)));

#define AS1 __attribute__((address_space(1)))
#define AS3 __attribute__((address_space(3)))

__device__ __forceinline__ void g2lds16(const void* g, void* l) {
    __builtin_amdgcn_global_load_lds((AS1 const void*)g, (AS3 void*)l, 16, 0, 0);
}

// Half-wave dword exchange: a' = {a.lo, b.lo}, b' = {a.hi, b.hi}
#if __has_builtin(__builtin_amdgcn_permlane32_swap)
typedef unsigned uint2v __attribute__((ext_vector_type(2)));
__device__ __forceinline__ void plswap(unsigned &a, unsigned &b) {
    uint2v r = __builtin_amdgcn_permlane32_swap(a, b, false, false);
    a = r[0]; b = r[1];
}
#else
__device__ __forceinline__ void plswap(unsigned &a, unsigned &b) {
    unsigned bl = (unsigned)__shfl_xor((int)b, 32);
    unsigned ah = (unsigned)__shfl_xor((int)a, 32);
    bool hi = (threadIdx.x & 32) != 0;
    unsigned na = hi ? bl : a;
    unsigned nb = hi ? b  : ah;
    a = na; b = nb;
}
#endif

__device__ __forceinline__ unsigned pk2(float x, float y) {
    bf16x2 t; t[0] = (__bf16)x; t[1] = (__bf16)y;
    return __builtin_bit_cast(unsigned, t);
}

// ---------------------------------------------------------------------------
// Kernel: prep = cast X fp32->bf16 (blocks 0..2047, 8 elems/thread)
//              + transpose 4 weights fp32 -> bf16 Wt[n][k] (blocks 2048..2303)
// Wq additionally scaled by QSCALE (folds attention scale + log2e into Q).
// ---------------------------------------------------------------------------
__global__ __launch_bounds__(256) void prep(const float* __restrict__ X,
                                            const float* __restrict__ W0,
                                            const float* __restrict__ W1,
                                            const float* __restrict__ W2,
                                            const float* __restrict__ W3,
                                            __bf16* __restrict__ Xb,
                                            __bf16* __restrict__ Wt_all) {
    int t = threadIdx.x;
    if (blockIdx.x < 2048) {
        size_t i = ((size_t)blockIdx.x * 256 + t) * 8;
        float4 v0 = *(const float4*)(X + i);
        float4 v1 = *(const float4*)(X + i + 4);
        bf16x8 o;
        o[0] = (__bf16)v0.x; o[1] = (__bf16)v0.y; o[2] = (__bf16)v0.z; o[3] = (__bf16)v0.w;
        o[4] = (__bf16)v1.x; o[5] = (__bf16)v1.y; o[6] = (__bf16)v1.z; o[7] = (__bf16)v1.w;
        *(bf16x8*)(Xb + i) = o;
        return;
    }
    int bid = blockIdx.x - 2048;
    int z = bid >> 6, rem = bid & 63;
    int by = rem >> 3, bx = rem & 7;
    const float* W = (z == 0) ? W0 : (z == 1) ? W1 : (z == 2) ? W2 : W3;
    float wsc = (z == 0) ? QSCALE : 1.0f;
    __bf16* Wt = Wt_all + (size_t)z * 65536;
    __shared__ float tile[32][33];
    int r0 = by * 32, c0 = bx * 32;
#pragma unroll
    for (int e = 0; e < 4; e++) {
        int idx = t + e * 256; int r = idx >> 5, c = idx & 31;
        tile[r][c] = W[(r0 + r) * 256 + c0 + c];
    }
    __syncthreads();
#pragma unroll
    for (int e = 0; e < 4; e++) {
        int idx = t + e * 256; int r = idx >> 5, c = idx & 31;
        Wt[(c0 + r) * 256 + (r0 + c)] = (__bf16)(tile[c][r] * wsc);
    }
}

// ---------------------------------------------------------------------------
// Kernel: NT GEMM  C[m][n] = sum_k A[m][k] * Wt[n][k] + bias[n]
// z=0,1 -> bf16 row-major into outb (+z stride); z=2 -> transposed-per-head
// write into Vt[b][h][dh][s]. out_is_f32 -> fp32 row-major into outf.
//
// R10: K-loop pipelined with the VERIFIED attn staging schedule (R3/R5):
// ring-3 x 8KB per operand (48KB LDS), prologue stages steps 0,1; per step:
// counted vmcnt(4) [step s landed, s+1 stays in flight] -> raw s_barrier
// [step s-1's readers done] -> STAGE(s+2) into the slot read at s-1 ->
// compute step s. Replaces the naive 2-barrier/K-step structure whose
// compiler-forced vmcnt(0) drain exposed ~500-900cy of memory latency on
// EVERY one of the 8 K-steps (m233: that drain is ~70% of the 2-phase
// structure's time). __launch_bounds__(256,3): 48KB -> 3 blocks/CU.
// ---------------------------------------------------------------------------
__global__ __launch_bounds__(256, 3) void gemm_bt(const __bf16* __restrict__ A,
                                                  const __bf16* __restrict__ Wt_all,
                                                  const float* __restrict__ bias0,
                                                  const float* __restrict__ bias1,
                                                  const float* __restrict__ bias2,
                                                  __bf16* __restrict__ outb,
                                                  __bf16* __restrict__ voutb,
                                                  float* __restrict__ outf,
                                                  int out_is_f32, float bsc0) {
    constexpr int K = 256;
    // 3 ring slots per operand: slot = 128 rows x 32 cols bf16 = 8KB
    __shared__ __attribute__((aligned(16))) __bf16 As[3 * 4096];
    __shared__ __attribute__((aligned(16))) __bf16 Bs[3 * 4096];

    int t = threadIdx.x;
    int lane = t & 63, w = t >> 6;
    int wr = w >> 1, wc = w & 1;
    int l16 = lane & 15, quad = lane >> 4;
    int mbase = blockIdx.x * 128;
    int nbase = blockIdx.y * 128;
    int z = blockIdx.z;
    const __bf16* Bt = Wt_all + (size_t)z * 65536;
    const float* bias = (z == 0) ? bias0 : (z == 1) ? bias1 : bias2;
    float bscale = (z == 0) ? bsc0 : 1.0f;

    f32x4 acc[4][4] = {};

    int srow = t >> 2;
    int sseg = (t & 3) * 8;

    // Stage K-step (32 cols) at col offset kk into ring slot (4 DMAs/thread)
#define GSTAGE(kk, slot) do {                                                  \
        g2lds16(A  + (size_t)(mbase +      srow) * K + (kk) + sseg,            \
                (char*)As + (slot) * 8192 +        t * 16);                    \
        g2lds16(A  + (size_t)(mbase + 64 + srow) * K + (kk) + sseg,            \
                (char*)As + (slot) * 8192 + 4096 + t * 16);                    \
        g2lds16(Bt + (size_t)(nbase +      srow) * K + (kk) + sseg,            \
                (char*)Bs + (slot) * 8192 +        t * 16);                    \
        g2lds16(Bt + (size_t)(nbase + 64 + srow) * K + (kk) + sseg,            \
                (char*)Bs + (slot) * 8192 + 4096 + t * 16);                    \
    } while (0)

    GSTAGE(0, 0);
    GSTAGE(32, 1);

    int rs = 0, ps = 2;   // read slot (s%3), prefetch slot ((s+2)%3)
#pragma unroll 1
    for (int s = 0; s < 8; s++) {
        if (s < 7) asm volatile("s_waitcnt vmcnt(4)" ::: "memory");  // step s landed
        else       asm volatile("s_waitcnt vmcnt(0)" ::: "memory");
        asm volatile("s_barrier" ::: "memory");   // step s-1 readers done
        if (s < 6) GSTAGE((s + 2) * 32, ps);      // slot ps read at s-1: drained

        bf16x8 a[4], b[4];
#pragma unroll
        for (int i = 0; i < 4; i++)
            a[i] = *(const bf16x8*)(As + rs * 4096 + (wr * 64 + i * 16 + l16) * 32 + quad * 8);
#pragma unroll
        for (int j = 0; j < 4; j++)
            b[j] = *(const bf16x8*)(Bs + rs * 4096 + (wc * 64 + j * 16 + l16) * 32 + quad * 8);
#pragma unroll
        for (int i = 0; i < 4; i++)
#pragma unroll
            for (int j = 0; j < 4; j++)
                acc[i][j] = __builtin_amdgcn_mfma_f32_16x16x32_bf16(a[i], b[j], acc[i][j], 0, 0, 0);

        rs = (rs == 2) ? 0 : rs + 1;
        ps = (ps == 2) ? 0 : ps + 1;
    }
#undef GSTAGE

#pragma unroll
    for (int i = 0; i < 4; i++) {
#pragma unroll
        for (int j = 0; j < 4; j++) {
            int col = nbase + wc * 64 + j * 16 + l16;
            float bv = bias[col] * bscale;
            int row0 = mbase + wr * 64 + i * 16 + quad * 4;
            if (out_is_f32) {
#pragma unroll
                for (int r = 0; r < 4; r++)
                    outf[(size_t)(row0 + r) * 256 + col] = acc[i][j][r] + bv;
            } else if (z == 2) {
                // V: write transposed per head -> Vt[(b*H+h)*64+dh][s]
                int hcol = col >> 6, dh = col & 63;
                int bidx = row0 >> 12, s0 = row0 & 4095;
                bf16x4 pk;
#pragma unroll
                for (int r = 0; r < 4; r++) pk[r] = (__bf16)(acc[i][j][r] + bv);
                *(bf16x4*)(voutb + ((size_t)(bidx * 4 + hcol) * 64 + dh) * 4096 + s0) = pk;
            } else {
#pragma unroll
                for (int r = 0; r < 4; r++)
                    outb[(size_t)z * ((size_t)M_TOTAL * 256) + (size_t)(row0 + r) * 256 + col] =
                        (__bf16)(acc[i][j][r] + bv);
            }
        }
    }
}

// ---------------------------------------------------------------------------
// Kernel: flash attention, S^T form, 32x32x16 MFMA, in-register P.
// R5 VERBATIM (best verified: 79.7us). 512 blocks x 4 waves (256 thr),
// 2x2 split: kw = w&1 (key half), qw2 = w>>1 (query half); 32 keys x 64
// queries per wave per 64-key tile. Software-pipelined QK one tile ahead,
// ring-4 x 16KB, prefetch dist 3, vmcnt(4), single barrier per iter.
// Occupancy 2 waves/SIMD (reg-pinned; R1/R2/R4/R6 proved chasing more is a
// dead end; R8/R9 proved the L2-direct variant is worse).
// Q pre-scaled by 0.125*log2e -> p = exp2(s). XCD swizzle: 2 heads per XCD.
// ---------------------------------------------------------------------------
__global__ __launch_bounds__(256, 2) void attn(const __bf16* __restrict__ Qb,
                                               const __bf16* __restrict__ Kb,
                                               const __bf16* __restrict__ Vt,
                                               __bf16* __restrict__ Ctx) {
    // 64 KB = 4 slots x 16KB {Ks 8KB, Vs 8KB}, seg-swizzled.
    // Epilogue reuse: [0,32K) acc dumps (2x16KB), [32K,33K) lsum dumps,
    // [36864,55296) 2 x (64 x 72) bf16 transpose tiles.
    __shared__ __attribute__((aligned(16))) __bf16 smem[32768];

    int t = threadIdx.x;
    int lane = t & 63, w = t >> 6;
    int l31 = lane & 31, hh = lane >> 5;
    int kw = w & 1, qw2 = w >> 1;

    // XCD swizzle: lin%8 = XCD; 2 heads per XCD
    int lin = blockIdx.x;
    int xcd = lin & 7, j = lin >> 3;
    int bh = xcd * 2 + (j & 1);
    int qblk = j >> 1;               // 0..31
    int b = bh >> 2, hd = bh & 3;
    int qw = qblk * 128 + qw2 * 64;  // this wave's first query

    const __bf16* Kbase = Kb + (size_t)b * S_ * 256 + hd * 64;
    const __bf16* Vbase = Vt + (size_t)bh * 64 * S_;

    // Q B-fragments (pre-scaled): n = query = qt*32+l31, k = dh = ks*16+hh*8+e
    bf16x8 qf[4][2];
#pragma unroll
    for (int ks = 0; ks < 4; ks++)
#pragma unroll
        for (int qt = 0; qt < 2; qt++)
            qf[ks][qt] = *(const bf16x8*)(Qb + (size_t)(b * S_ + qw + qt * 32 + l31) * 256
                                              + hd * 64 + ks * 16 + hh * 8);

    f32x16 acc[2][2] = {};   // [mt][qt]: dh = mt*32+..., query = qt*32+l31
    float lsum[2] = {0.f, 0.f};

    int srow = t >> 3;    // 0..31
    int sseg = t & 7;

    // Stage 64-key tile at key offset kv into ring slot (16KB), 4 DMAs/thread
#define STAGE(kv, slot) do {                                                   \
        char* mk = (char*)smem + (slot) * 16384;                               \
        char* mv = mk + 8192;                                                  \
        _Pragma("unroll")                                                      \
        for (int c = 0; c < 2; c++) {                                          \
            int rr = c * 32 + srow;                                            \
            int gseg = (sseg ^ (rr & 7)) * 8;                                  \
            g2lds16(Kbase + (size_t)((kv) + rr) * 256 + gseg,                  \
                    mk + c * 4096 + t * 16);                                   \
            g2lds16(Vbase + (size_t)rr * S_ + (kv) + gseg,                     \
                    mv + c * 4096 + t * 16);                                   \
        }                                                                      \
    } while (0)

    // QK^T for TILE into SN (this wave's 32 keys x its 64 queries)
#define QKSTEP(TILE, SN) do {                                                  \
        __bf16* Ksp = (__bf16*)((char*)smem + ((TILE) & 3) * 16384);           \
        bf16x8 kfv[4];                                                         \
        _Pragma("unroll")                                                      \
        for (int ks = 0; ks < 4; ks++) {                                       \
            int slot = (ks * 2 + hh) ^ (l31 & 7);                              \
            kfv[ks] = *(const bf16x8*)(Ksp + (kw * 32 + l31) * 64 + slot * 8); \
        }                                                                      \
        _Pragma("unroll")                                                      \
        for (int qt = 0; qt < 2; qt++) SN[qt] = (f32x16){};                    \
        _Pragma("unroll")                                                      \
        for (int ks = 0; ks < 4; ks++)                                         \
            _Pragma("unroll")                                                  \
            for (int qt = 0; qt < 2; qt++)                                     \
                SN[qt] = __builtin_amdgcn_mfma_f32_32x32x16_bf16(              \
                    kfv[ks], qf[ks][qt], SN[qt], 0, 0, 0);                     \
    } while (0)

    // softmax + PV for tile IT, scores in SC
#define SMPV(IT, SC) do {                                                      \
        __bf16* Vsp = (__bf16*)((char*)smem + ((IT) & 3) * 16384) + 4096;      \
        unsigned dd[2][8];                                                     \
        _Pragma("unroll")                                                      \
        for (int qt = 0; qt < 2; qt++) {                                       \
            float p[16];                                                       \
            _Pragma("unroll")                                                  \
            for (int r = 0; r < 16; r++)                                       \
                p[r] = __builtin_amdgcn_exp2f(SC[qt][r]);                      \
            float s0 = ((p[0]+p[1])+(p[2]+p[3]))+((p[4]+p[5])+(p[6]+p[7]));    \
            float s1 = ((p[8]+p[9])+(p[10]+p[11]))+((p[12]+p[13])+(p[14]+p[15])); \
            lsum[qt] += s0 + s1;                                               \
            _Pragma("unroll")                                                  \
            for (int m = 0; m < 4; m++) {                                      \
                dd[qt][m*2]   = pk2(p[4*m],   p[4*m+1]);                       \
                dd[qt][m*2+1] = pk2(p[4*m+2], p[4*m+3]);                       \
            }                                                                  \
        }                                                                      \
        _Pragma("unroll")                                                      \
        for (int tt = 0; tt < 2; tt++) {                                       \
            int tks = kw * 2 + tt;                                             \
            bf16x8 pf[2];                                                      \
            _Pragma("unroll")                                                  \
            for (int qt = 0; qt < 2; qt++) {                                   \
                unsigned x0 = dd[qt][4*tt],   y0 = dd[qt][4*tt+2];             \
                unsigned x1 = dd[qt][4*tt+1], y1 = dd[qt][4*tt+3];             \
                plswap(x0, y0);                                                \
                plswap(x1, y1);                                                \
                union { unsigned u[4]; bf16x8 v; } c;                          \
                c.u[0] = x0; c.u[1] = x1; c.u[2] = y0; c.u[3] = y1;            \
                pf[qt] = c.v;                                                  \
            }                                                                  \
            _Pragma("unroll")                                                  \
            for (int mt = 0; mt < 2; mt++) {                                   \
                int slot = (tks * 2 + hh) ^ (l31 & 7);                         \
                bf16x8 vf = *(const bf16x8*)(Vsp + (mt*32 + l31)*64 + slot*8); \
                _Pragma("unroll")                                              \
                for (int qt = 0; qt < 2; qt++)                                 \
                    acc[mt][qt] = __builtin_amdgcn_mfma_f32_32x32x16_bf16(     \
                        vf, pf[qt], acc[mt][qt], 0, 0, 0);                     \
            }                                                                  \
        }                                                                      \
    } while (0)

    // One pipelined iteration: wait tile IT+1; barrier; stage IT+3;
    // QK(IT+1)->SN (MFMA pipe); softmax+PV(IT) on SC (VALU + MFMA).
#define BODY(IT, SC, SN) do {                                                  \
        if ((IT) < 62) asm volatile("s_waitcnt vmcnt(4)" ::: "memory");        \
        else           asm volatile("s_waitcnt vmcnt(0)" ::: "memory");        \
        asm volatile("s_barrier" ::: "memory");                                \
        if ((IT) <= 60) STAGE(((IT) + 3) * 64, ((IT) + 3) & 3);                \
        if ((IT) < 63) QKSTEP((IT) + 1, SN);                                   \
        SMPV(IT, SC);                                                          \
    } while (0)

    f32x16 stA[2], stB[2];

    // Prologue: fill 3 ring slots, compute QK(0) -> stA
    STAGE(0, 0);
    STAGE(64, 1);
    STAGE(128, 2);
    asm volatile("s_waitcnt vmcnt(8)" ::: "memory");   // tile 0 landed
    asm volatile("s_barrier" ::: "memory");
    QKSTEP(0, stA);

    for (int it = 0; it < 64; it += 2) {
        BODY(it,     stA, stB);
        BODY(it + 1, stB, stA);
    }
#undef BODY
#undef SMPV
#undef QKSTEP
#undef STAGE

    // In-wave denom over this wave's keys (halves hold disjoint key sets)
#pragma unroll
    for (int qt = 0; qt < 2; qt++)
        lsum[qt] += __shfl_xor(lsum[qt], 32);

    // --- Cross-wave merge between kw partners (same qw2) ---
    __syncthreads();
    float* lsd = (float*)((char*)smem + 32768);
    if (kw == 1) {
#pragma unroll
        for (int mt = 0; mt < 2; mt++)
#pragma unroll
            for (int qt = 0; qt < 2; qt++)
#pragma unroll
                for (int g = 0; g < 4; g++) {
                    f32x4 v;
#pragma unroll
                    for (int e = 0; e < 4; e++) v[e] = acc[mt][qt][4 * g + e];
                    *(f32x4*)((char*)smem + qw2 * 16384
                              + ((mt * 2 + qt) * 4 + g) * 1024 + lane * 16) = v;
                }
        lsd[qw2 * 128 + lane * 2 + 0] = lsum[0];
        lsd[qw2 * 128 + lane * 2 + 1] = lsum[1];
    }
    __syncthreads();
    if (kw == 0) {
        float inv[2];
#pragma unroll
        for (int qt = 0; qt < 2; qt++)
            inv[qt] = 1.f / (lsum[qt] + lsd[qw2 * 128 + lane * 2 + qt]);
#pragma unroll
        for (int mt = 0; mt < 2; mt++)
#pragma unroll
            for (int qt = 0; qt < 2; qt++)
#pragma unroll
                for (int g = 0; g < 4; g++) {
                    f32x4 v = *(const f32x4*)((char*)smem + qw2 * 16384
                                              + ((mt * 2 + qt) * 4 + g) * 1024 + lane * 16);
#pragma unroll
                    for (int e = 0; e < 4; e++) acc[mt][qt][4 * g + e] += v[e];
                }

        // Epilogue: normalize, per-wave LDS transpose (64x72), coalesced store
        __bf16* Es = smem + 18432 + qw2 * 4608;   // bytes 36864 + qw2*9216
#pragma unroll
        for (int qt = 0; qt < 2; qt++)
#pragma unroll
            for (int mt = 0; mt < 2; mt++)
#pragma unroll
                for (int rg = 0; rg < 4; rg++) {
                    bf16x4 ov;
#pragma unroll
                    for (int e = 0; e < 4; e++)
                        ov[e] = (__bf16)(acc[mt][qt][4 * rg + e] * inv[qt]);
                    int dhb = mt * 32 + rg * 8 + 4 * hh;
                    *(bf16x4*)(Es + (qt * 32 + l31) * 72 + dhb) = ov;
                }
#pragma unroll
        for (int pass = 0; pass < 8; pass++) {
            int q = pass * 8 + (lane >> 3);
            int col = (lane & 7) * 8;
            bf16x8 val = *(const bf16x8*)(Es + q * 72 + col);
            *(bf16x8*)(Ctx + (size_t)(b * S_ + qw + q) * 256 + hd * 64 + col) = val;
        }
    }
}

// ---------------------------------------------------------------------------
extern "C" void kernel_launch(void* const* d_in, const int* in_sizes, int n_in,
                              void* d_out, int out_size, void* d_ws, size_t ws_size,
                              hipStream_t stream) {
    const float* X  = (const float*)d_in[0];
    const float* Wq = (const float*)d_in[1];
    const float* bq = (const float*)d_in[2];
    const float* Wk = (const float*)d_in[3];
    const float* bk = (const float*)d_in[4];
    const float* Wv = (const float*)d_in[5];
    const float* bv = (const float*)d_in[6];
    const float* Wo = (const float*)d_in[7];
    const float* bo = (const float*)d_in[8];
    float* out = (float*)d_out;

    char* ws = (char*)d_ws;
    const size_t MB = 1024 * 1024;
    // [0,8MB) Xb (bf16 X), dead after QKV gemm -> reused as Ctx
    // [8,8.5MB) Wt; [8.5,16.5) Qb; [16.5,24.5) Kb; [24.5,32.5) Vt
    __bf16* Xb  = (__bf16*)(ws);
    __bf16* Ctx = (__bf16*)(ws);
    __bf16* Wt  = (__bf16*)(ws + 8 * MB);
    __bf16* Qb  = (__bf16*)(ws + 8 * MB + 512 * 1024);
    __bf16* Kb  = (__bf16*)((char*)Qb + 8 * MB);
    __bf16* Vt  = (__bf16*)((char*)Kb + 8 * MB);

    // 1. cast X -> bf16 + transpose/scale weights (fused)
    prep<<<dim3(2304), dim3(256), 0, stream>>>(X, Wq, Wk, Wv, Wo, Xb, Wt);
    // 2. QKV projections (ring-3 pipelined K-loop); V written transposed (Vt)
    gemm_bt<<<dim3(M_TOTAL / 128, 2, 3), dim3(256), 0, stream>>>(
        Xb, Wt, bq, bk, bv, Qb, Vt, nullptr, 0, QSCALE);
    // 3. flash attention -> Ctx  (R5 verbatim: 512 blocks x 4 waves, QK
    //    pipelined, ring-4)
    attn<<<dim3(512), dim3(256), 0, stream>>>(Qb, Kb, Vt, Ctx);
    // 4. output projection (fp32 out + bias, pipelined K-loop)
    gemm_bt<<<dim3(M_TOTAL / 128, 2, 1), dim3(256), 0, stream>>>(
        Ctx, Wt + 3 * 65536, bo, bo, bo, nullptr, nullptr, out, 1, 1.0f);
}

// Round 11
// 178.733 us; speedup vs baseline: 1.1142x; 1.0103x over previous
//
#include <hip/hip_runtime.h>
#include <cmath>

// Problem constants
#define B_  4
#define S_  4096
#define D_  256
#define H_  4
#define DH_ 64
#define M_TOTAL (B_*S_)   // 16384
#define QSCALE 0.1803368801111f   // 0.125 * log2(e), folded into Wq

typedef __bf16 bf16x8 __attribute__((ext_vector_type(8)));
typedef __bf16 bf16x4 __attribute__((ext_vector_type(4)));
typedef __bf16 bf16x2 __attribute__((ext_vector_type(2)));
typedef float  f32x4  __attribute__((ext_vector_type(4)));
typedef float  f32x16 __attribute__((ext_vector_type(16)));

#define AS1 __attribute__((address_space(1)))
#define AS3 __attribute__((address_space(3)))

__device__ __forceinline__ void g2lds16(const void* g, void* l) {
    __builtin_amdgcn_global_load_lds((AS1 const void*)g, (AS3 void*)l, 16, 0, 0);
}

// Half-wave dword exchange: a' = {a.lo, b.lo}, b' = {a.hi, b.hi}
#if __has_builtin(__builtin_amdgcn_permlane32_swap)
typedef unsigned uint2v __attribute__((ext_vector_type(2)));
__device__ __forceinline__ void plswap(unsigned &a, unsigned &b) {
    uint2v r = __builtin_amdgcn_permlane32_swap(a, b, false, false);
    a = r[0]; b = r[1];
}
#else
__device__ __forceinline__ void plswap(unsigned &a, unsigned &b) {
    unsigned bl = (unsigned)__shfl_xor((int)b, 32);
    unsigned ah = (unsigned)__shfl_xor((int)a, 32);
    bool hi = (threadIdx.x & 32) != 0;
    unsigned na = hi ? bl : a;
    unsigned nb = hi ? b  : ah;
    a = na; b = nb;
}
#endif

__device__ __forceinline__ unsigned pk2(float x, float y) {
    bf16x2 t; t[0] = (__bf16)x; t[1] = (__bf16)y;
    return __builtin_bit_cast(unsigned, t);
}

// ---------------------------------------------------------------------------
// Kernel: prep = cast X fp32->bf16 (blocks 0..2047, 8 elems/thread)
//              + transpose 4 weights fp32 -> bf16 Wt[n][k] (blocks 2048..2303)
// Wq additionally scaled by QSCALE (folds attention scale + log2e into Q).
// ---------------------------------------------------------------------------
__global__ __launch_bounds__(256) void prep(const float* __restrict__ X,
                                            const float* __restrict__ W0,
                                            const float* __restrict__ W1,
                                            const float* __restrict__ W2,
                                            const float* __restrict__ W3,
                                            __bf16* __restrict__ Xb,
                                            __bf16* __restrict__ Wt_all) {
    int t = threadIdx.x;
    if (blockIdx.x < 2048) {
        size_t i = ((size_t)blockIdx.x * 256 + t) * 8;
        float4 v0 = *(const float4*)(X + i);
        float4 v1 = *(const float4*)(X + i + 4);
        bf16x8 o;
        o[0] = (__bf16)v0.x; o[1] = (__bf16)v0.y; o[2] = (__bf16)v0.z; o[3] = (__bf16)v0.w;
        o[4] = (__bf16)v1.x; o[5] = (__bf16)v1.y; o[6] = (__bf16)v1.z; o[7] = (__bf16)v1.w;
        *(bf16x8*)(Xb + i) = o;
        return;
    }
    int bid = blockIdx.x - 2048;
    int z = bid >> 6, rem = bid & 63;
    int by = rem >> 3, bx = rem & 7;
    const float* W = (z == 0) ? W0 : (z == 1) ? W1 : (z == 2) ? W2 : W3;
    float wsc = (z == 0) ? QSCALE : 1.0f;
    __bf16* Wt = Wt_all + (size_t)z * 65536;
    __shared__ float tile[32][33];
    int r0 = by * 32, c0 = bx * 32;
#pragma unroll
    for (int e = 0; e < 4; e++) {
        int idx = t + e * 256; int r = idx >> 5, c = idx & 31;
        tile[r][c] = W[(r0 + r) * 256 + c0 + c];
    }
    __syncthreads();
#pragma unroll
    for (int e = 0; e < 4; e++) {
        int idx = t + e * 256; int r = idx >> 5, c = idx & 31;
        Wt[(c0 + r) * 256 + (r0 + c)] = (__bf16)(tile[c][r] * wsc);
    }
}

// ---------------------------------------------------------------------------
// Kernel: NT GEMM  C[m][n] = sum_k A[m][k] * Wt[n][k] + bias[n]
// z=0,1 -> bf16 row-major into outb (+z stride); z=2 -> transposed-per-head
// write into Vt[b][h][dh][s]. out_is_f32 -> fp32 row-major into outf.
//
// R11: XCD-LOCALITY GRID. 1-D grid, decoded so that all (nbase,z) readers
// of an A row-block satisfy mbase%8 == xcd (lin%8 = XCD dispatch model):
// A tile fetched from HBM once per XCD, re-served from that XCD's L2
// (16 mbase x 128KB = 2MB < 4MB L2). Old 3-D grid put the 6 readers of
// each A tile on 6 DIFFERENT XCDs -> ~6x A HBM traffic (48MB), invariant
// to K-loop schedule -- the R10 null result's leading explanation.
// K-loop: R10's ring-3 x 8KB/operand, counted vmcnt(4), 1 barrier/step.
// ---------------------------------------------------------------------------
__global__ __launch_bounds__(256, 3) void gemm_bt(const __bf16* __restrict__ A,
                                                  const __bf16* __restrict__ Wt_all,
                                                  const float* __restrict__ bias0,
                                                  const float* __restrict__ bias1,
                                                  const float* __restrict__ bias2,
                                                  __bf16* __restrict__ outb,
                                                  __bf16* __restrict__ voutb,
                                                  float* __restrict__ outf,
                                                  int out_is_f32, float bsc0) {
    constexpr int K = 256;
    // 3 ring slots per operand: slot = 128 rows x 32 cols bf16 = 8KB
    __shared__ __attribute__((aligned(16))) __bf16 As[3 * 4096];
    __shared__ __attribute__((aligned(16))) __bf16 Bs[3 * 4096];

    int t = threadIdx.x;
    int lane = t & 63, w = t >> 6;
    int wr = w >> 1, wc = w & 1;
    int l16 = lane & 15, quad = lane >> 4;

    // XCD-locality decode: xcd = lin%8; all nz variants of one mbase share it.
    int lin = blockIdx.x;
    int xcd = lin & 7, i = lin >> 3;
    int mb, nb, z;
    if (out_is_f32) {            // 256 blocks: i in [0,32) = 16 mb x 2 nb
        mb = i >> 1; nb = i & 1; z = 0;
    } else {                     // 768 blocks: i in [0,96) = 16 mb x 6 nz
        int nz = i % 6; mb = i / 6;
        z = nz % 3; nb = nz / 3;
    }
    int mbase = (mb * 8 + xcd) * 128;
    int nbase = nb * 128;

    const __bf16* Bt = Wt_all + (size_t)z * 65536;
    const float* bias = (z == 0) ? bias0 : (z == 1) ? bias1 : bias2;
    float bscale = (z == 0) ? bsc0 : 1.0f;

    f32x4 acc[4][4] = {};

    int srow = t >> 2;
    int sseg = (t & 3) * 8;

    // Stage K-step (32 cols) at col offset kk into ring slot (4 DMAs/thread)
#define GSTAGE(kk, slot) do {                                                  \
        g2lds16(A  + (size_t)(mbase +      srow) * K + (kk) + sseg,            \
                (char*)As + (slot) * 8192 +        t * 16);                    \
        g2lds16(A  + (size_t)(mbase + 64 + srow) * K + (kk) + sseg,            \
                (char*)As + (slot) * 8192 + 4096 + t * 16);                    \
        g2lds16(Bt + (size_t)(nbase +      srow) * K + (kk) + sseg,            \
                (char*)Bs + (slot) * 8192 +        t * 16);                    \
        g2lds16(Bt + (size_t)(nbase + 64 + srow) * K + (kk) + sseg,            \
                (char*)Bs + (slot) * 8192 + 4096 + t * 16);                    \
    } while (0)

    GSTAGE(0, 0);
    GSTAGE(32, 1);

    int rs = 0, ps = 2;   // read slot (s%3), prefetch slot ((s+2)%3)
#pragma unroll 1
    for (int s = 0; s < 8; s++) {
        if (s < 7) asm volatile("s_waitcnt vmcnt(4)" ::: "memory");  // step s landed
        else       asm volatile("s_waitcnt vmcnt(0)" ::: "memory");
        asm volatile("s_barrier" ::: "memory");   // step s-1 readers done
        if (s < 6) GSTAGE((s + 2) * 32, ps);      // slot ps read at s-1: drained

        bf16x8 a[4], b[4];
#pragma unroll
        for (int i2 = 0; i2 < 4; i2++)
            a[i2] = *(const bf16x8*)(As + rs * 4096 + (wr * 64 + i2 * 16 + l16) * 32 + quad * 8);
#pragma unroll
        for (int j = 0; j < 4; j++)
            b[j] = *(const bf16x8*)(Bs + rs * 4096 + (wc * 64 + j * 16 + l16) * 32 + quad * 8);
#pragma unroll
        for (int i2 = 0; i2 < 4; i2++)
#pragma unroll
            for (int j = 0; j < 4; j++)
                acc[i2][j] = __builtin_amdgcn_mfma_f32_16x16x32_bf16(a[i2], b[j], acc[i2][j], 0, 0, 0);

        rs = (rs == 2) ? 0 : rs + 1;
        ps = (ps == 2) ? 0 : ps + 1;
    }
#undef GSTAGE

#pragma unroll
    for (int i2 = 0; i2 < 4; i2++) {
#pragma unroll
        for (int j = 0; j < 4; j++) {
            int col = nbase + wc * 64 + j * 16 + l16;
            float bv = bias[col] * bscale;
            int row0 = mbase + wr * 64 + i2 * 16 + quad * 4;
            if (out_is_f32) {
#pragma unroll
                for (int r = 0; r < 4; r++)
                    outf[(size_t)(row0 + r) * 256 + col] = acc[i2][j][r] + bv;
            } else if (z == 2) {
                // V: write transposed per head -> Vt[(b*H+h)*64+dh][s]
                int hcol = col >> 6, dh = col & 63;
                int bidx = row0 >> 12, s0 = row0 & 4095;
                bf16x4 pk;
#pragma unroll
                for (int r = 0; r < 4; r++) pk[r] = (__bf16)(acc[i2][j][r] + bv);
                *(bf16x4*)(voutb + ((size_t)(bidx * 4 + hcol) * 64 + dh) * 4096 + s0) = pk;
            } else {
#pragma unroll
                for (int r = 0; r < 4; r++)
                    outb[(size_t)z * ((size_t)M_TOTAL * 256) + (size_t)(row0 + r) * 256 + col] =
                        (__bf16)(acc[i2][j][r] + bv);
            }
        }
    }
}

// ---------------------------------------------------------------------------
// Kernel: flash attention, S^T form, 32x32x16 MFMA, in-register P.
// R5 schedule (best verified: 79.7us), R11 codegen tweak: the 64-iteration
// loop is restructured as 15 x 4 fully-unrolled bodies (it = i4*4 + k) plus
// an explicit 4-body tail, so every ring-slot index (it+c)&3 is a
// COMPILE-TIME constant -> LDS addresses become base+immediate, removing
// the per-body slot-address VALU chains. Hazard distances, vmcnt counts,
// and barrier placement are byte-identical to R5 (tail reproduces R5's
// edge conditions exactly).
// 512 blocks x 4 waves, 2x2 split (kw key half, qw2 query half); ring-4 x
// 16KB, prefetch dist 3, counted vmcnt(4), 1 barrier/iter; QK one tile
// ahead (stA/stB alternation). Occupancy 2 waves/SIMD (reg-pinned).
// Q pre-scaled by 0.125*log2e -> p = exp2(s). XCD swizzle: 2 heads per XCD.
// ---------------------------------------------------------------------------
__global__ __launch_bounds__(256, 2) void attn(const __bf16* __restrict__ Qb,
                                               const __bf16* __restrict__ Kb,
                                               const __bf16* __restrict__ Vt,
                                               __bf16* __restrict__ Ctx) {
    // 64 KB = 4 slots x 16KB {Ks 8KB, Vs 8KB}, seg-swizzled.
    // Epilogue reuse: [0,32K) acc dumps (2x16KB), [32K,33K) lsum dumps,
    // [36864,55296) 2 x (64 x 72) bf16 transpose tiles.
    __shared__ __attribute__((aligned(16))) __bf16 smem[32768];

    int t = threadIdx.x;
    int lane = t & 63, w = t >> 6;
    int l31 = lane & 31, hh = lane >> 5;
    int kw = w & 1, qw2 = w >> 1;

    // XCD swizzle: lin%8 = XCD; 2 heads per XCD
    int lin = blockIdx.x;
    int xcd = lin & 7, j = lin >> 3;
    int bh = xcd * 2 + (j & 1);
    int qblk = j >> 1;               // 0..31
    int b = bh >> 2, hd = bh & 3;
    int qw = qblk * 128 + qw2 * 64;  // this wave's first query

    const __bf16* Kbase = Kb + (size_t)b * S_ * 256 + hd * 64;
    const __bf16* Vbase = Vt + (size_t)bh * 64 * S_;

    // Q B-fragments (pre-scaled): n = query = qt*32+l31, k = dh = ks*16+hh*8+e
    bf16x8 qf[4][2];
#pragma unroll
    for (int ks = 0; ks < 4; ks++)
#pragma unroll
        for (int qt = 0; qt < 2; qt++)
            qf[ks][qt] = *(const bf16x8*)(Qb + (size_t)(b * S_ + qw + qt * 32 + l31) * 256
                                              + hd * 64 + ks * 16 + hh * 8);

    f32x16 acc[2][2] = {};   // [mt][qt]: dh = mt*32+..., query = qt*32+l31
    float lsum[2] = {0.f, 0.f};

    int srow = t >> 3;    // 0..31
    int sseg = t & 7;

    // Stage 64-key tile at key offset kv into ring slot (16KB), 4 DMAs/thread
#define STAGE(kv, slot) do {                                                   \
        char* mk = (char*)smem + (slot) * 16384;                               \
        char* mv = mk + 8192;                                                  \
        _Pragma("unroll")                                                      \
        for (int c = 0; c < 2; c++) {                                          \
            int rr = c * 32 + srow;                                            \
            int gseg = (sseg ^ (rr & 7)) * 8;                                  \
            g2lds16(Kbase + (size_t)((kv) + rr) * 256 + gseg,                  \
                    mk + c * 4096 + t * 16);                                   \
            g2lds16(Vbase + (size_t)rr * S_ + (kv) + gseg,                     \
                    mv + c * 4096 + t * 16);                                   \
        }                                                                      \
    } while (0)

    // QK^T for TILE into SN (this wave's 32 keys x its 64 queries)
#define QKSTEP(TILE, SN) do {                                                  \
        __bf16* Ksp = (__bf16*)((char*)smem + ((TILE) & 3) * 16384);           \
        bf16x8 kfv[4];                                                         \
        _Pragma("unroll")                                                      \
        for (int ks = 0; ks < 4; ks++) {                                       \
            int slot = (ks * 2 + hh) ^ (l31 & 7);                              \
            kfv[ks] = *(const bf16x8*)(Ksp + (kw * 32 + l31) * 64 + slot * 8); \
        }                                                                      \
        _Pragma("unroll")                                                      \
        for (int qt = 0; qt < 2; qt++) SN[qt] = (f32x16){};                    \
        _Pragma("unroll")                                                      \
        for (int ks = 0; ks < 4; ks++)                                         \
            _Pragma("unroll")                                                  \
            for (int qt = 0; qt < 2; qt++)                                     \
                SN[qt] = __builtin_amdgcn_mfma_f32_32x32x16_bf16(              \
                    kfv[ks], qf[ks][qt], SN[qt], 0, 0, 0);                     \
    } while (0)

    // softmax + PV for tile IT, scores in SC
#define SMPV(IT, SC) do {                                                      \
        __bf16* Vsp = (__bf16*)((char*)smem + ((IT) & 3) * 16384) + 4096;      \
        unsigned dd[2][8];                                                     \
        _Pragma("unroll")                                                      \
        for (int qt = 0; qt < 2; qt++) {                                       \
            float p[16];                                                       \
            _Pragma("unroll")                                                  \
            for (int r = 0; r < 16; r++)                                       \
                p[r] = __builtin_amdgcn_exp2f(SC[qt][r]);                      \
            float s0 = ((p[0]+p[1])+(p[2]+p[3]))+((p[4]+p[5])+(p[6]+p[7]));    \
            float s1 = ((p[8]+p[9])+(p[10]+p[11]))+((p[12]+p[13])+(p[14]+p[15])); \
            lsum[qt] += s0 + s1;                                               \
            _Pragma("unroll")                                                  \
            for (int m = 0; m < 4; m++) {                                      \
                dd[qt][m*2]   = pk2(p[4*m],   p[4*m+1]);                       \
                dd[qt][m*2+1] = pk2(p[4*m+2], p[4*m+3]);                       \
            }                                                                  \
        }                                                                      \
        _Pragma("unroll")                                                      \
        for (int tt = 0; tt < 2; tt++) {                                       \
            int tks = kw * 2 + tt;                                             \
            bf16x8 pf[2];                                                      \
            _Pragma("unroll")                                                  \
            for (int qt = 0; qt < 2; qt++) {                                   \
                unsigned x0 = dd[qt][4*tt],   y0 = dd[qt][4*tt+2];             \
                unsigned x1 = dd[qt][4*tt+1], y1 = dd[qt][4*tt+3];             \
                plswap(x0, y0);                                                \
                plswap(x1, y1);                                                \
                union { unsigned u[4]; bf16x8 v; } c;                          \
                c.u[0] = x0; c.u[1] = x1; c.u[2] = y0; c.u[3] = y1;            \
                pf[qt] = c.v;                                                  \
            }                                                                  \
            _Pragma("unroll")                                                  \
            for (int mt = 0; mt < 2; mt++) {                                   \
                int slot = (tks * 2 + hh) ^ (l31 & 7);                         \
                bf16x8 vf = *(const bf16x8*)(Vsp + (mt*32 + l31)*64 + slot*8); \
                _Pragma("unroll")                                              \
                for (int qt = 0; qt < 2; qt++)                                 \
                    acc[mt][qt] = __builtin_amdgcn_mfma_f32_32x32x16_bf16(     \
                        vf, pf[qt], acc[mt][qt], 0, 0, 0);                     \
            }                                                                  \
        }                                                                      \
    } while (0)

    // Full-steam body (valid for IT in [0,60)): all R5 conditions are
    // constant-true here. vmcnt(4): STAGE(IT+1) (issued 2 bodies ago)
    // drained, STAGE(IT+2) (1 body ago) left in flight.
#define BODYF(IT, SC, SN) do {                                                 \
        asm volatile("s_waitcnt vmcnt(4)" ::: "memory");                       \
        asm volatile("s_barrier" ::: "memory");                                \
        STAGE(((IT) + 3) * 64, ((IT) + 3) & 3);                                \
        QKSTEP((IT) + 1, SN);                                                  \
        SMPV(IT, SC);                                                          \
    } while (0)

    f32x16 stA[2], stB[2];

    // Prologue: fill 3 ring slots, compute QK(0) -> stA
    STAGE(0, 0);
    STAGE(64, 1);
    STAGE(128, 2);
    asm volatile("s_waitcnt vmcnt(8)" ::: "memory");   // tile 0 landed
    asm volatile("s_barrier" ::: "memory");
    QKSTEP(0, stA);

    // Bodies 0..59: it = i4*4 + k keeps every (it+c)&3 compile-time.
#pragma unroll 1
    for (int i4 = 0; i4 < 15; i4++) {
        int it = i4 * 4;
        BODYF(it,     stA, stB);
        BODYF(it + 1, stB, stA);
        BODYF(it + 2, stA, stB);
        BODYF(it + 3, stB, stA);
    }

    // Tail bodies 60..63 (R5 edge conditions, unrolled)
    asm volatile("s_waitcnt vmcnt(4)" ::: "memory");   // it=60
    asm volatile("s_barrier" ::: "memory");
    STAGE(63 * 64, 3);
    QKSTEP(61, stB);
    SMPV(60, stA);
    asm volatile("s_waitcnt vmcnt(4)" ::: "memory");   // it=61
    asm volatile("s_barrier" ::: "memory");
    QKSTEP(62, stA);
    SMPV(61, stB);
    asm volatile("s_waitcnt vmcnt(0)" ::: "memory");   // it=62
    asm volatile("s_barrier" ::: "memory");
    QKSTEP(63, stB);
    SMPV(62, stA);
    asm volatile("s_waitcnt vmcnt(0)" ::: "memory");   // it=63
    asm volatile("s_barrier" ::: "memory");
    SMPV(63, stB);
#undef BODYF
#undef SMPV
#undef QKSTEP
#undef STAGE

    // In-wave denom over this wave's keys (halves hold disjoint key sets)
#pragma unroll
    for (int qt = 0; qt < 2; qt++)
        lsum[qt] += __shfl_xor(lsum[qt], 32);

    // --- Cross-wave merge between kw partners (same qw2) ---
    __syncthreads();
    float* lsd = (float*)((char*)smem + 32768);
    if (kw == 1) {
#pragma unroll
        for (int mt = 0; mt < 2; mt++)
#pragma unroll
            for (int qt = 0; qt < 2; qt++)
#pragma unroll
                for (int g = 0; g < 4; g++) {
                    f32x4 v;
#pragma unroll
                    for (int e = 0; e < 4; e++) v[e] = acc[mt][qt][4 * g + e];
                    *(f32x4*)((char*)smem + qw2 * 16384
                              + ((mt * 2 + qt) * 4 + g) * 1024 + lane * 16) = v;
                }
        lsd[qw2 * 128 + lane * 2 + 0] = lsum[0];
        lsd[qw2 * 128 + lane * 2 + 1] = lsum[1];
    }
    __syncthreads();
    if (kw == 0) {
        float inv[2];
#pragma unroll
        for (int qt = 0; qt < 2; qt++)
            inv[qt] = 1.f / (lsum[qt] + lsd[qw2 * 128 + lane * 2 + qt]);
#pragma unroll
        for (int mt = 0; mt < 2; mt++)
#pragma unroll
            for (int qt = 0; qt < 2; qt++)
#pragma unroll
                for (int g = 0; g < 4; g++) {
                    f32x4 v = *(const f32x4*)((char*)smem + qw2 * 16384
                                              + ((mt * 2 + qt) * 4 + g) * 1024 + lane * 16);
#pragma unroll
                    for (int e = 0; e < 4; e++) acc[mt][qt][4 * g + e] += v[e];
                }

        // Epilogue: normalize, per-wave LDS transpose (64x72), coalesced store
        __bf16* Es = smem + 18432 + qw2 * 4608;   // bytes 36864 + qw2*9216
#pragma unroll
        for (int qt = 0; qt < 2; qt++)
#pragma unroll
            for (int mt = 0; mt < 2; mt++)
#pragma unroll
                for (int rg = 0; rg < 4; rg++) {
                    bf16x4 ov;
#pragma unroll
                    for (int e = 0; e < 4; e++)
                        ov[e] = (__bf16)(acc[mt][qt][4 * rg + e] * inv[qt]);
                    int dhb = mt * 32 + rg * 8 + 4 * hh;
                    *(bf16x4*)(Es + (qt * 32 + l31) * 72 + dhb) = ov;
                }
#pragma unroll
        for (int pass = 0; pass < 8; pass++) {
            int q = pass * 8 + (lane >> 3);
            int col = (lane & 7) * 8;
            bf16x8 val = *(const bf16x8*)(Es + q * 72 + col);
            *(bf16x8*)(Ctx + (size_t)(b * S_ + qw + q) * 256 + hd * 64 + col) = val;
        }
    }
}

// ---------------------------------------------------------------------------
extern "C" void kernel_launch(void* const* d_in, const int* in_sizes, int n_in,
                              void* d_out, int out_size, void* d_ws, size_t ws_size,
                              hipStream_t stream) {
    const float* X  = (const float*)d_in[0];
    const float* Wq = (const float*)d_in[1];
    const float* bq = (const float*)d_in[2];
    const float* Wk = (const float*)d_in[3];
    const float* bk = (const float*)d_in[4];
    const float* Wv = (const float*)d_in[5];
    const float* bv = (const float*)d_in[6];
    const float* Wo = (const float*)d_in[7];
    const float* bo = (const float*)d_in[8];
    float* out = (float*)d_out;

    char* ws = (char*)d_ws;
    const size_t MB = 1024 * 1024;
    // [0,8MB) Xb (bf16 X), dead after QKV gemm -> reused as Ctx
    // [8,8.5MB) Wt; [8.5,16.5) Qb; [16.5,24.5) Kb; [24.5,32.5) Vt
    __bf16* Xb  = (__bf16*)(ws);
    __bf16* Ctx = (__bf16*)(ws);
    __bf16* Wt  = (__bf16*)(ws + 8 * MB);
    __bf16* Qb  = (__bf16*)(ws + 8 * MB + 512 * 1024);
    __bf16* Kb  = (__bf16*)((char*)Qb + 8 * MB);
    __bf16* Vt  = (__bf16*)((char*)Kb + 8 * MB);

    // 1. cast X -> bf16 + transpose/scale weights (fused)
    prep<<<dim3(2304), dim3(256), 0, stream>>>(X, Wq, Wk, Wv, Wo, Xb, Wt);
    // 2. QKV projections, XCD-locality grid (768 = 8 xcd x 16 mb x 6 nz);
    //    V written transposed (Vt)
    gemm_bt<<<dim3(768), dim3(256), 0, stream>>>(
        Xb, Wt, bq, bk, bv, Qb, Vt, nullptr, 0, QSCALE);
    // 3. flash attention -> Ctx (R5 schedule, const-folded ring addressing)
    attn<<<dim3(512), dim3(256), 0, stream>>>(Qb, Kb, Vt, Ctx);
    // 4. output projection, XCD-locality grid (256 = 8 x 16 x 2)
    gemm_bt<<<dim3(256), dim3(256), 0, stream>>>(
        Ctx, Wt + 3 * 65536, bo, bo, bo, nullptr, nullptr, out, 1, 1.0f);
}